// Round 26
// baseline (330.588 us; speedup 1.0000x reference)
//
#include <hip/hip_runtime.h>
#include <hip/hip_bf16.h>

// ChebyKAN: y[b,o] = sum_{i,d} T_d(tanh(x[b,i])) * W[i,o,d]
// GEMM M=16384, N=1024, K=9216 with generated A (packed-fp16 Chebyshev recurrence).
// R22: ZERO-LDS GEMM. B-fragments read direct-to-register from wt (each read =
//      64 lanes x 16B = one contiguous 1KB window, perfectly coalesced; block's
//      wt slice 2MB = L2-resident/XCD). 2 rotating B reg-sets, depth-1 prefetch.
//      No __shared__, no barriers, no manual waitcnt -- compiler-scheduled,
//      waves fully independent. deg0->bias hoist kept; prep fusion kept.

#define WSCALE 4096.0f
#define INV_WSCALE (1.0f/4096.0f)

typedef _Float16 f16;
typedef __fp16   hf2  __attribute__((ext_vector_type(2)));
typedef _Float16 f16x2v __attribute__((ext_vector_type(2)));
typedef _Float16 f16x8 __attribute__((ext_vector_type(8)));
typedef float    f32x4 __attribute__((ext_vector_type(4)));
typedef float    f32x4u __attribute__((ext_vector_type(4), aligned(4)));
typedef float    f32x2u __attribute__((ext_vector_type(2), aligned(4)));
typedef float    f32x16 __attribute__((ext_vector_type(16)));

union F16x8u { hf2 h2[4]; f16x8 v8; };

// ---- fused prep: wt-transpose (blocks 0..1023), bias (1024..1087), t2 (1088..9279)
__global__ __launch_bounds__(256) void prep_kernel(const float* __restrict__ x,
                                                   const float* __restrict__ cc,
                                                   f16* __restrict__ t2,
                                                   f16* __restrict__ wt,
                                                   float* __restrict__ bias) {
  __shared__ char smem[18432];
  const int bid = blockIdx.x;
  const int t   = threadIdx.x;

  if (bid < 1024) {
    // ---- wt transpose: cc [I][O][9] f32 -> wt (R5 layout), block = (ic,ncol,u)
    f16* s16 = (f16*)smem;
    const int u    = bid & 3;
    const int ncol = (bid >> 2) & 7;
    const int ic   = bid >> 5;
    const int i2   = t >> 4;
    const int o2   = t & 15;
    const int i0   = i2 * 2, o0 = o2 * 2;
    const int h    = i0 >> 4;
    const int kl   = (i0 >> 3) & 1;
    const int e    = i0 & 7;

    float va[2][18];
#pragma unroll
    for (int ii = 0; ii < 2; ++ii) {
      const float* g = cc + ((size_t)(ic * 32 + i0 + ii) * 1024
                             + (ncol * 128 + u * 32 + o0)) * 9;
      f32x4u a = *(const f32x4u*)(g);
      f32x4u b = *(const f32x4u*)(g + 4);
      f32x4u c4 = *(const f32x4u*)(g + 8);
      f32x4u d4 = *(const f32x4u*)(g + 12);
      f32x2u e2 = *(const f32x2u*)(g + 16);
#pragma unroll
      for (int j = 0; j < 4; ++j) { va[ii][j] = a[j]; va[ii][4 + j] = b[j];
                                    va[ii][8 + j] = c4[j]; va[ii][12 + j] = d4[j]; }
      va[ii][16] = e2[0]; va[ii][17] = e2[1];
    }

#pragma unroll
    for (int oo = 0; oo < 2; ++oo) {
      const int ol = o0 + oo;
      const int r  = ol & 15, q = ol >> 4;
      const int rk = (r >> 1) & 3;
      const int vsl = (kl * 2 + q) ^ rk;
      const int jj = h * 16 + r;
#pragma unroll
      for (int d = 0; d < 9; ++d) {
        f16x2v pv = { (f16)(va[0][oo * 9 + d] * WSCALE),
                      (f16)(va[1][oo * 9 + d] * WSCALE) };
        *(f16x2v*)(&s16[(d * 128 + jj * 4 + vsl) * 8 + e]) = pv;
      }
    }
    __syncthreads();

#pragma unroll
    for (int w = 0; w < 5; ++w) {
      int cidx = t + 256 * w;
      if (cidx < 1152) {
        f16x8 val = *(const f16x8*)(&s16[cidx * 8]);
        int d = cidx >> 7, rem = cidx & 127;
        *(f16x8*)(wt + (size_t)((d * 32 + ic) * 8 + ncol) * 4096 + u * 1024 + rem * 8) = val;
      }
    }
  } else if (bid < 1088) {
    // ---- bias[o] = sum_i cc[i][o][0] (T_0 term, exact f32); 16 thr per o
    float* red = (float*)smem;
    const int ol = t >> 4;
    const int sl = t & 15;
    const int o  = (bid - 1024) * 16 + ol;
    float s = 0.f;
    const float* p = cc + (size_t)(sl * 64) * 9216 + (size_t)o * 9;
#pragma unroll 4
    for (int i = 0; i < 64; ++i) s += p[(size_t)i * 9216];
    red[t] = s;
    __syncthreads();
    if (sl < 8) red[t] += red[t + 8];
    __syncthreads();
    if (sl < 4) red[t] += red[t + 4];
    __syncthreads();
    if (sl < 2) red[t] += red[t + 2];
    __syncthreads();
    if (sl == 0) bias[o] = red[t] + red[t + 1];
  } else {
    // ---- t2 = 2*tanh(x) as f16 (8 elems/thread)
    size_t gid = (size_t)(bid - 1088) * 256 + t;
    const float* p = x + gid * 8;
    f32x4 a = *(const f32x4*)p;
    f32x4 b = *(const f32x4*)(p + 4);
    float tf[8];
#pragma unroll
    for (int e = 0; e < 8; ++e) {
      float xx = (e < 4) ? a[e] : b[e - 4];
      tf[e] = 1.f - 2.f * __builtin_amdgcn_rcpf(__expf(2.f * xx) + 1.f);
    }
    F16x8u u;
#pragma unroll
    for (int q = 0; q < 4; ++q)
      u.h2[q] = __builtin_amdgcn_cvt_pkrtz(tf[2 * q], tf[2 * q + 1]);
    f16x8 v = u.v8 + u.v8;
    *(f16x8*)(t2 + gid * 8) = v;
  }
}

// ---- kernel 2: zero-LDS fused basis-gen + GEMM, 128x128 tile, 4 waves 64x64
__global__ __launch_bounds__(256, 3) void cheby_gemm(const f16* __restrict__ t2g,
                                                     const f16* __restrict__ wt,
                                                     const float* __restrict__ bias,
                                                     float* __restrict__ out) {
  const int tid  = threadIdx.x;
  const int wid  = tid >> 6;
  const int lane = tid & 63;
  const int lr   = lane & 31;
  const int lh   = lane >> 5;
  const int wm   = wid >> 1;
  const int wn   = wid & 1;
  const int mrow = blockIdx.x >> 3;
  const int ncol = blockIdx.x & 7;
  const int m0   = mrow * 128 + wm * 64;
  const int n0   = ncol * 128 + wn * 64;
  // per-lane B base inside a (d,c) region (f16 units); regions stride 32768
  const f16* bsrc = wt + (size_t)ncol * 4096 + wn * 2048
                    + ((lane & 15) * 4 + ((lane >> 4) ^ ((lane >> 1) & 3))) * 8;

  f32x16 acc[2][2];
#pragma unroll
  for (int a = 0; a < 2; ++a)
#pragma unroll
    for (int b = 0; b < 2; ++b)
#pragma unroll
      for (int j = 0; j < 16; ++j) acc[a][b][j] = 0.f;

  const f16x8 ones  = {(f16)1,(f16)1,(f16)1,(f16)1,(f16)1,(f16)1,(f16)1,(f16)1};
  const f16x8 half8 = {(f16)0.5f,(f16)0.5f,(f16)0.5f,(f16)0.5f,
                       (f16)0.5f,(f16)0.5f,(f16)0.5f,(f16)0.5f};
  f16x8 t2v[2][2];

  auto loadx = [&](int cn) {   // 4 VMEM f16x8 -> t2v (consumed immediately after)
#pragma unroll
    for (int mb = 0; mb < 2; ++mb)
#pragma unroll
      for (int h = 0; h < 2; ++h)
        t2v[mb][h] = *(const f16x8*)(t2g + (size_t)(m0 + mb * 32 + lr) * 1024
                                         + cn * 32 + h * 16 + lh * 8);
  };

// LBG: 4 coalesced global 16B reads for degree D of chunk C into BD
#define LBG(BD, D, C)                                                          \
  {                                                                            \
    const f16* p = bsrc + (size_t)((D) * 32 + (C)) * 32768;                    \
    BD[0][0] = *(const f16x8*)(p);        BD[0][1] = *(const f16x8*)(p + 512); \
    BD[1][0] = *(const f16x8*)(p + 1024); BD[1][1] = *(const f16x8*)(p + 1536);\
  }

#define REC(NEW, S1, S2)                                                       \
  _Pragma("unroll") for (int mb = 0; mb < 2; ++mb)                             \
    _Pragma("unroll") for (int h = 0; h < 2; ++h)                              \
      NEW[mb][h] = __builtin_elementwise_fma(t2v[mb][h], S1[mb][h], -S2[mb][h]);

#define M8(AF, BD)                                                             \
  {                                                                            \
    _Pragma("unroll") for (int nb = 0; nb < 2; ++nb)                           \
      _Pragma("unroll") for (int mb = 0; mb < 2; ++mb) {                       \
        acc[mb][nb] = __builtin_amdgcn_mfma_f32_32x32x16_f16(AF[mb][0], BD[nb][0], \
                                                             acc[mb][nb], 0, 0, 0); \
        acc[mb][nb] = __builtin_amdgcn_mfma_f32_32x32x16_f16(AF[mb][1], BD[nb][1], \
                                                             acc[mb][nb], 0, 0, 0); \
      }                                                                        \
  }

  f16x8 onesA[2][2];
#pragma unroll
  for (int mb = 0; mb < 2; ++mb)
#pragma unroll
    for (int h = 0; h < 2; ++h) onesA[mb][h] = ones;

  f16x8 bfA[2][2], bfB[2][2];
  f16x8 A1[2][2], A2[2][2], A3[2][2], A4[2][2], A5[2][2], A6[2][2], A7[2][2], A8[2][2];

  // prologue: B(deg1,chunk0) into bfA; x(chunk0) into t2v
  LBG(bfA, 1, 0)
  loadx(0);

  for (int c = 0; c < 32; ++c) {
    const int cn = (c < 31) ? c + 1 : 31;   // clamp keeps prefetch in-bounds

    // A1 = t (t2v loaded at end of previous iteration / prologue)
#pragma unroll
    for (int mb = 0; mb < 2; ++mb)
#pragma unroll
      for (int h = 0; h < 2; ++h) A1[mb][h] = t2v[mb][h] * half8;

    LBG(bfB, 2, c)                          M8(A1, bfA)   // deg1
    LBG(bfA, 3, c)  REC(A2, A1, onesA)      M8(A2, bfB)   // deg2
    LBG(bfB, 4, c)  REC(A3, A2, A1)         M8(A3, bfA)   // deg3
    LBG(bfA, 5, c)  REC(A4, A3, A2)         M8(A4, bfB)   // deg4
    LBG(bfB, 6, c)  REC(A5, A4, A3)         M8(A5, bfA)   // deg5
    LBG(bfA, 7, c)  REC(A6, A5, A4)         M8(A6, bfB)   // deg6
    LBG(bfB, 8, c)  REC(A7, A6, A5)         M8(A7, bfA)   // deg7
    LBG(bfA, 1, cn) REC(A8, A7, A6)                        // prefetch next deg1
    if (c < 31) loadx(c + 1);               // next-chunk t2 (after A1 consumed t2v)
    M8(A8, bfB)                                           // deg8
  }
#undef LBG
#undef REC
#undef M8

  // epilogue: C/D map col=lane&31, row=(j&3)+8*(j>>2)+4*(lane>>5); add bias
  float bno[2];
  bno[0] = bias[n0 + lr];
  bno[1] = bias[n0 + 32 + lr];
#pragma unroll
  for (int mb = 0; mb < 2; ++mb)
#pragma unroll
    for (int nb = 0; nb < 2; ++nb)
#pragma unroll
      for (int j = 0; j < 16; ++j) {
        int row = m0 + mb * 32 + 4 * lh + (j & 3) + 8 * (j >> 2);
        int col = n0 + nb * 32 + lr;
        out[(size_t)row * 1024 + col] = acc[mb][nb][j] * INV_WSCALE + bno[nb];
      }
}

// ---- fallback (ws too small): in-GEMM tanh, full 9 degrees, chunk-level sync
__global__ __launch_bounds__(512, 2) void cheby_gemm_fb(const float* __restrict__ x,
                                                        const f16* __restrict__ wt,
                                                        float* __restrict__ out) {
  __shared__ f16 bbuf[18][4096];
  const int tid  = threadIdx.x;
  const int wid  = tid >> 6;
  const int lane = tid & 63;
  const int lr   = lane & 31;
  const int lh   = lane >> 5;
  const int wm   = wid >> 1;
  const int wn   = wid & 1;
  const int mrow = blockIdx.x >> 3;
  const int ncol = blockIdx.x & 7;
  const int m0   = mrow * 256 + wm * 64;
  const int n0   = ncol * 128 + wn * 64;
  const int rbase = wn * 2048 + ((lane & 15) * 4 + ((lane >> 4) ^ ((lane >> 1) & 3))) * 8;

  auto stage = [&](int cn, int dn, int buf) {
    const f16* src = wt + (size_t)(dn * 32 + cn) * 32768 + (size_t)ncol * 4096;
    __builtin_amdgcn_global_load_lds(
        (const __attribute__((address_space(1))) unsigned*)(src + tid * 8),
        (__attribute__((address_space(3))) unsigned*)(&bbuf[buf][wid * 512]),
        16, 0, 0);
  };
  auto stage9 = [&](int cn, int b0) {
#pragma unroll
    for (int d = 0; d < 9; ++d) stage(cn, d, b0 + d);
  };

  f32x16 acc[2][2];
#pragma unroll
  for (int a = 0; a < 2; ++a)
#pragma unroll
    for (int b = 0; b < 2; ++b)
#pragma unroll
      for (int j = 0; j < 16; ++j) acc[a][b][j] = 0.f;

  const f16x8 ones  = {(f16)1,(f16)1,(f16)1,(f16)1,(f16)1,(f16)1,(f16)1,(f16)1};
  const f16x8 half8 = {(f16)0.5f,(f16)0.5f,(f16)0.5f,(f16)0.5f,
                       (f16)0.5f,(f16)0.5f,(f16)0.5f,(f16)0.5f};
  f16x8 t2v[2][2], t2n[2][2];
  f32x4 xf[2][2][2];

  auto loadx = [&](int cn) {
#pragma unroll
    for (int mb = 0; mb < 2; ++mb)
#pragma unroll
      for (int h = 0; h < 2; ++h) {
        const float* p = x + (size_t)(m0 + mb * 32 + lr) * 1024 + cn * 32 + h * 16 + lh * 8;
        xf[mb][h][0] = *(const f32x4*)p;
        xf[mb][h][1] = *(const f32x4*)(p + 4);
      }
  };
  auto dotanh = [&]() {
#pragma unroll
    for (int mb = 0; mb < 2; ++mb)
#pragma unroll
      for (int h = 0; h < 2; ++h) {
        float tf[8];
#pragma unroll
        for (int e = 0; e < 8; ++e) {
          float xx = (e < 4) ? xf[mb][h][0][e] : xf[mb][h][1][e - 4];
          tf[e] = 1.f - 2.f * __builtin_amdgcn_rcpf(__expf(2.f * xx) + 1.f);
        }
        F16x8u u;
#pragma unroll
        for (int q = 0; q < 4; ++q)
          u.h2[q] = __builtin_amdgcn_cvt_pkrtz(tf[2 * q], tf[2 * q + 1]);
        t2n[mb][h] = u.v8 + u.v8;
      }
  };

#define REC(NEW, S1, S2)                                                       \
  _Pragma("unroll") for (int mb = 0; mb < 2; ++mb)                             \
    _Pragma("unroll") for (int h = 0; h < 2; ++h)                              \
      NEW[mb][h] = __builtin_elementwise_fma(t2v[mb][h], S1[mb][h], -S2[mb][h]);
#define CLUSTER(AF, DIDX)                                                      \
  {                                                                            \
    const f16* bb = &bbuf[0][0] + sbase + (DIDX) * 4096 + rbase;               \
    f16x8 bf[2][2];                                                            \
    _Pragma("unroll") for (int nb = 0; nb < 2; ++nb)                           \
      _Pragma("unroll") for (int h = 0; h < 2; ++h)                            \
        bf[nb][h] = *(const f16x8*)&bb[nb * 1024 + h * 512];                   \
    _Pragma("unroll") for (int nb = 0; nb < 2; ++nb)                           \
      _Pragma("unroll") for (int mb = 0; mb < 2; ++mb) {                       \
        acc[mb][nb] = __builtin_amdgcn_mfma_f32_32x32x16_f16(AF[mb][0], bf[nb][0], \
                                                             acc[mb][nb], 0, 0, 0); \
        acc[mb][nb] = __builtin_amdgcn_mfma_f32_32x32x16_f16(AF[mb][1], bf[nb][1], \
                                                             acc[mb][nb], 0, 0, 0); \
      }                                                                        \
  }

  stage9(0, 0);
  loadx(0);
  dotanh();

  f16x8 onesA[2][2];
#pragma unroll
  for (int mb = 0; mb < 2; ++mb)
#pragma unroll
    for (int h = 0; h < 2; ++h) onesA[mb][h] = ones;

  for (int c = 0; c < 32; ++c) {
    const bool lastc = (c == 31);
    const int  sbase = (c & 1) * 36864;
    const int  nbase = (1 - (c & 1)) * 9;

    asm volatile("s_waitcnt vmcnt(8)" ::: "memory");
    __builtin_amdgcn_s_barrier();

    f16x8 A1[2][2], A2[2][2], A3[2][2], A4[2][2], A5[2][2], A6[2][2], A7[2][2], A8[2][2];
#pragma unroll
    for (int mb = 0; mb < 2; ++mb)
#pragma unroll
      for (int h = 0; h < 2; ++h) {
        t2v[mb][h] = t2n[mb][h];
        A1[mb][h]  = t2v[mb][h] * half8;
      }
    if (!lastc) { stage9(c + 1, nbase); loadx(c + 1); }

    CLUSTER(onesA, 0)
    CLUSTER(A1, 1)
    REC(A2, A1, onesA)  CLUSTER(A2, 2)
    REC(A3, A2, A1)     CLUSTER(A3, 3)
    REC(A4, A3, A2)     CLUSTER(A4, 4)
    REC(A5, A4, A3)     CLUSTER(A5, 5)
    REC(A6, A5, A4)     CLUSTER(A6, 6)
    REC(A7, A6, A5)     CLUSTER(A7, 7)
    REC(A8, A7, A6)     CLUSTER(A8, 8)
    if (!lastc) dotanh();
  }
#undef REC
#undef CLUSTER

#pragma unroll
  for (int mb = 0; mb < 2; ++mb)
#pragma unroll
    for (int nb = 0; nb < 2; ++nb)
#pragma unroll
      for (int j = 0; j < 16; ++j) {
        int row = m0 + mb * 32 + 4 * lh + (j & 3) + 8 * (j >> 2);
        int col = n0 + nb * 32 + lr;
        out[(size_t)row * 1024 + col] = acc[mb][nb][j] * INV_WSCALE;
      }
}

extern "C" void kernel_launch(void* const* d_in, const int* in_sizes, int n_in,
                              void* d_out, int out_size, void* d_ws, size_t ws_size,
                              hipStream_t stream) {
  const float* x  = (const float*)d_in[0];
  const float* cc = (const float*)d_in[1];
  f16*   wt   = (f16*)d_ws;                          // 18,874,368 B
  f16*   t2   = (f16*)((char*)d_ws + 18874368);      // 33,554,432 B
  float* bias = (float*)((char*)d_ws + 52428800);    // 4,096 B
  float* out  = (float*)d_out;

  if (ws_size >= 52432896) {
    hipLaunchKernelGGL(prep_kernel, dim3(9280), dim3(256), 0, stream, x, cc, t2, wt, bias);
    hipLaunchKernelGGL(cheby_gemm, dim3(1024), dim3(256), 0, stream, t2, wt, bias, out);
  } else {
    hipLaunchKernelGGL(prep_kernel, dim3(1024), dim3(256), 0, stream, x, cc, t2, wt, bias);
    hipLaunchKernelGGL(cheby_gemm_fb, dim3(512), dim3(512), 0, stream, x, wt, out);
  }
}

// Round 27
// 283.724 us; speedup vs baseline: 1.1652x; 1.1652x over previous
//
#include <hip/hip_runtime.h>
#include <hip/hip_bf16.h>

// ChebyKAN: y[b,o] = sum_{i,d} T_d(tanh(x[b,i])) * W[i,o,d]
// GEMM M=16384, N=1024, K=9216 with generated A (packed-fp16 Chebyshev recurrence).
// R23 = R21 (best: 285.5us total, gemm 258us @ MfmaUtil 56%): deg0->bias hoist,
//      ring-5 LDS staging w/ counted vmcnt (tail-corrected), fused prep.
//      R22's zero-LDS variant regressed (L2 latency exposed) -> reverted.

#define WSCALE 4096.0f
#define INV_WSCALE (1.0f/4096.0f)

typedef _Float16 f16;
typedef __fp16   hf2  __attribute__((ext_vector_type(2)));
typedef _Float16 f16x2v __attribute__((ext_vector_type(2)));
typedef _Float16 f16x8 __attribute__((ext_vector_type(8)));
typedef float    f32x4 __attribute__((ext_vector_type(4)));
typedef float    f32x4u __attribute__((ext_vector_type(4), aligned(4)));
typedef float    f32x2u __attribute__((ext_vector_type(2), aligned(4)));
typedef float    f32x16 __attribute__((ext_vector_type(16)));

union F16x8u { hf2 h2[4]; f16x8 v8; };

// ---- fused prep: wt-transpose (blocks 0..1023), bias (1024..1087), t2 (1088..9279)
__global__ __launch_bounds__(256) void prep_kernel(const float* __restrict__ x,
                                                   const float* __restrict__ cc,
                                                   f16* __restrict__ t2,
                                                   f16* __restrict__ wt,
                                                   float* __restrict__ bias) {
  __shared__ char smem[18432];
  const int bid = blockIdx.x;
  const int t   = threadIdx.x;

  if (bid < 1024) {
    // ---- wt transpose: cc [I][O][9] f32 -> wt (R5 layout), block = (ic,ncol,u)
    f16* s16 = (f16*)smem;
    const int u    = bid & 3;
    const int ncol = (bid >> 2) & 7;
    const int ic   = bid >> 5;
    const int i2   = t >> 4;
    const int o2   = t & 15;
    const int i0   = i2 * 2, o0 = o2 * 2;
    const int h    = i0 >> 4;
    const int kl   = (i0 >> 3) & 1;
    const int e    = i0 & 7;

    float va[2][18];
#pragma unroll
    for (int ii = 0; ii < 2; ++ii) {
      const float* g = cc + ((size_t)(ic * 32 + i0 + ii) * 1024
                             + (ncol * 128 + u * 32 + o0)) * 9;
      f32x4u a = *(const f32x4u*)(g);
      f32x4u b = *(const f32x4u*)(g + 4);
      f32x4u c4 = *(const f32x4u*)(g + 8);
      f32x4u d4 = *(const f32x4u*)(g + 12);
      f32x2u e2 = *(const f32x2u*)(g + 16);
#pragma unroll
      for (int j = 0; j < 4; ++j) { va[ii][j] = a[j]; va[ii][4 + j] = b[j];
                                    va[ii][8 + j] = c4[j]; va[ii][12 + j] = d4[j]; }
      va[ii][16] = e2[0]; va[ii][17] = e2[1];
    }

#pragma unroll
    for (int oo = 0; oo < 2; ++oo) {
      const int ol = o0 + oo;
      const int r  = ol & 15, q = ol >> 4;
      const int rk = (r >> 1) & 3;
      const int vsl = (kl * 2 + q) ^ rk;
      const int jj = h * 16 + r;
#pragma unroll
      for (int d = 0; d < 9; ++d) {
        f16x2v pv = { (f16)(va[0][oo * 9 + d] * WSCALE),
                      (f16)(va[1][oo * 9 + d] * WSCALE) };
        *(f16x2v*)(&s16[(d * 128 + jj * 4 + vsl) * 8 + e]) = pv;
      }
    }
    __syncthreads();

#pragma unroll
    for (int w = 0; w < 5; ++w) {
      int cidx = t + 256 * w;
      if (cidx < 1152) {
        f16x8 val = *(const f16x8*)(&s16[cidx * 8]);
        int d = cidx >> 7, rem = cidx & 127;
        *(f16x8*)(wt + (size_t)((d * 32 + ic) * 8 + ncol) * 4096 + u * 1024 + rem * 8) = val;
      }
    }
  } else if (bid < 1088) {
    // ---- bias[o] = sum_i cc[i][o][0] (T_0 term, exact f32); 16 thr per o
    float* red = (float*)smem;
    const int ol = t >> 4;
    const int sl = t & 15;
    const int o  = (bid - 1024) * 16 + ol;
    float s = 0.f;
    const float* p = cc + (size_t)(sl * 64) * 9216 + (size_t)o * 9;
#pragma unroll 4
    for (int i = 0; i < 64; ++i) s += p[(size_t)i * 9216];
    red[t] = s;
    __syncthreads();
    if (sl < 8) red[t] += red[t + 8];
    __syncthreads();
    if (sl < 4) red[t] += red[t + 4];
    __syncthreads();
    if (sl < 2) red[t] += red[t + 2];
    __syncthreads();
    if (sl == 0) bias[o] = red[t] + red[t + 1];
  } else {
    // ---- t2 = 2*tanh(x) as f16 (8 elems/thread)
    size_t gid = (size_t)(bid - 1088) * 256 + t;
    const float* p = x + gid * 8;
    f32x4 a = *(const f32x4*)p;
    f32x4 b = *(const f32x4*)(p + 4);
    float tf[8];
#pragma unroll
    for (int e = 0; e < 8; ++e) {
      float xx = (e < 4) ? a[e] : b[e - 4];
      tf[e] = 1.f - 2.f * __builtin_amdgcn_rcpf(__expf(2.f * xx) + 1.f);
    }
    F16x8u u;
#pragma unroll
    for (int q = 0; q < 4; ++q)
      u.h2[q] = __builtin_amdgcn_cvt_pkrtz(tf[2 * q], tf[2 * q + 1]);
    f16x8 v = u.v8 + u.v8;
    *(f16x8*)(t2 + gid * 8) = v;
  }
}

// ---- kernel 2: fused basis-gen + GEMM, 128x128 tile, 4 waves of 64m x 64n,
//      8 degrees/chunk (deg 0 hoisted to bias), ring-5 LDS (40KB)
__global__ __launch_bounds__(256, 3) void cheby_gemm(const f16* __restrict__ t2g,
                                                     const f16* __restrict__ wt,
                                                     const float* __restrict__ bias,
                                                     float* __restrict__ out) {
  __shared__ f16 bbuf[5][4096];

  const int tid  = threadIdx.x;
  const int wid  = tid >> 6;
  const int lane = tid & 63;
  const int lr   = lane & 31;
  const int lh   = lane >> 5;
  const int wm   = wid >> 1;
  const int wn   = wid & 1;
  const int mrow = blockIdx.x >> 3;
  const int ncol = blockIdx.x & 7;
  const int m0   = mrow * 128 + wm * 64;
  const int n0   = ncol * 128 + wn * 64;
  const int rbase = wn * 2048 + ((lane & 15) * 4 + ((lane >> 4) ^ ((lane >> 1) & 3))) * 8;

  auto stage = [&](int cn, int dn, int slot) {
    const f16* src = wt + (size_t)(dn * 32 + cn) * 32768 + (size_t)ncol * 4096;
    __builtin_amdgcn_global_load_lds(
        (const __attribute__((address_space(1))) unsigned*)(src + tid * 8),
        (__attribute__((address_space(3))) unsigned*)(&bbuf[slot][wid * 512]),
        16, 0, 0);
    __builtin_amdgcn_global_load_lds(
        (const __attribute__((address_space(1))) unsigned*)(src + 2048 + tid * 8),
        (__attribute__((address_space(3))) unsigned*)(&bbuf[slot][wid * 512 + 2048]),
        16, 0, 0);
  };

  f32x16 acc[2][2];
#pragma unroll
  for (int a = 0; a < 2; ++a)
#pragma unroll
    for (int b = 0; b < 2; ++b)
#pragma unroll
      for (int j = 0; j < 16; ++j) acc[a][b][j] = 0.f;

  const f16x8 ones  = {(f16)1,(f16)1,(f16)1,(f16)1,(f16)1,(f16)1,(f16)1,(f16)1};
  const f16x8 half8 = {(f16)0.5f,(f16)0.5f,(f16)0.5f,(f16)0.5f,
                       (f16)0.5f,(f16)0.5f,(f16)0.5f,(f16)0.5f};
  f16x8 t2v[2][2], t2n[2][2];

  auto loadx = [&](int cn) {   // 4 VMEM f16x8 -> t2n
#pragma unroll
    for (int mb = 0; mb < 2; ++mb)
#pragma unroll
      for (int h = 0; h < 2; ++h)
        t2n[mb][h] = *(const f16x8*)(t2g + (size_t)(m0 + mb * 32 + lr) * 1024
                                         + cn * 32 + h * 16 + lh * 8);
  };

#define REC(NEW, S1, S2)                                                       \
  _Pragma("unroll") for (int mb = 0; mb < 2; ++mb)                             \
    _Pragma("unroll") for (int h = 0; h < 2; ++h)                              \
      NEW[mb][h] = __builtin_elementwise_fma(t2v[mb][h], S1[mb][h], -S2[mb][h]);

#define LB(BD, SLOT)                                                           \
  {                                                                            \
    const f16* bb = &bbuf[0][0] + (SLOT) * 4096 + rbase;                       \
    BD[0][0] = *(const f16x8*)&bb[0];    BD[0][1] = *(const f16x8*)&bb[512];   \
    BD[1][0] = *(const f16x8*)&bb[1024]; BD[1][1] = *(const f16x8*)&bb[1536];  \
  }

#define M8(AF, BD)                                                             \
  {                                                                            \
    _Pragma("unroll") for (int nb = 0; nb < 2; ++nb)                           \
      _Pragma("unroll") for (int mb = 0; mb < 2; ++mb) {                       \
        acc[mb][nb] = __builtin_amdgcn_mfma_f32_32x32x16_f16(AF[mb][0], BD[nb][0], \
                                                             acc[mb][nb], 0, 0, 0); \
        acc[mb][nb] = __builtin_amdgcn_mfma_f32_32x32x16_f16(AF[mb][1], BD[nb][1], \
                                                             acc[mb][nb], 0, 0, 0); \
      }                                                                        \
  }

#define ADOPT                                                                  \
  _Pragma("unroll") for (int mb = 0; mb < 2; ++mb)                             \
    _Pragma("unroll") for (int h = 0; h < 2; ++h) {                            \
      t2v[mb][h] = t2n[mb][h];                                                 \
      A1[mb][h]  = t2v[mb][h] * half8;                                         \
    }

#define VMB(N)                                                                 \
  asm volatile("s_waitcnt vmcnt(" #N ")" ::: "memory");                        \
  __builtin_amdgcn_s_barrier();

  f16x8 onesA[2][2];
#pragma unroll
  for (int mb = 0; mb < 2; ++mb)
#pragma unroll
    for (int h = 0; h < 2; ++h) onesA[mb][h] = ones;

  f16x8 bfA[2][2], bfB[2][2];
  f16x8 A1[2][2], A2[2][2], A3[2][2], A4[2][2], A5[2][2], A6[2][2], A7[2][2], A8[2][2];
  // roles: s1..s4 = slots of degs 1..4 of current chunk; s5 = free slot
  int s1 = 0, s2 = 1, s3 = 2, s4 = 3, s5 = 4;

  // prologue: loadx(0); stage chunk0 degs 1..4 -> s1..s4
  loadx(0);
  stage(0, 1, s1); stage(0, 2, s2); stage(0, 3, s3); stage(0, 4, s4);

  for (int c = 0; c < 31; ++c) {
    // PH1 (deg1): prove degs1,2 (+loadx(c), older) -> vmcnt(4)
    VMB(4)
    LB(bfA, s1)                                // deg1
    ADOPT                                      // consumes t2n BEFORE loadx(c+1)
    stage(c, 5, s5);
    loadx(c + 1);
    LB(bfB, s2)                                // deg2
    M8(A1, bfA)

    VMB(8) stage(c, 6, s1); LB(bfA, s3) REC(A2, A1, onesA) M8(A2, bfB)   // PH2
    VMB(8) stage(c, 7, s2); LB(bfB, s4) REC(A3, A2, A1)    M8(A3, bfA)   // PH3
    VMB(8) stage(c, 8, s3); LB(bfA, s5) REC(A4, A3, A2)    M8(A4, bfB)   // PH4
    VMB(4) stage(c + 1, 1, s4); LB(bfB, s1) REC(A5, A4, A3) M8(A5, bfA)  // PH5
    VMB(4) stage(c + 1, 2, s5); LB(bfA, s2) REC(A6, A5, A4) M8(A6, bfB)  // PH6
    VMB(4) stage(c + 1, 3, s1); LB(bfB, s3) REC(A7, A6, A5) M8(A7, bfA)  // PH7
    stage(c + 1, 4, s2);                                                 // PH8
    REC(A8, A7, A6) M8(A8, bfB)

    // role rotation for next chunk: degs1..4 in s4,s5,s1,s2; free = s3
    { int n1 = s4, n2 = s5, n3 = s1, n4 = s2, n5 = s3;
      s1 = n1; s2 = n2; s3 = n3; s4 = n4; s5 = n5; }
  }

  // ---- tail chunk c=31: queue drains faster (no next-chunk stages):
  // waits PH1=4, PH2-5=4, PH6=2, PH7=0 (R20-verified deterministic)
  {
    VMB(4)
    LB(bfA, s1)
    ADOPT
    stage(31, 5, s5);
    LB(bfB, s2)
    M8(A1, bfA)

    VMB(4) stage(31, 6, s1); LB(bfA, s3) REC(A2, A1, onesA) M8(A2, bfB)
    VMB(4) stage(31, 7, s2); LB(bfB, s4) REC(A3, A2, A1)    M8(A3, bfA)
    VMB(4) stage(31, 8, s3); LB(bfA, s5) REC(A4, A3, A2)    M8(A4, bfB)
    VMB(4) LB(bfB, s1) REC(A5, A4, A3) M8(A5, bfA)
    VMB(2) LB(bfA, s2) REC(A6, A5, A4) M8(A6, bfB)
    VMB(0) LB(bfB, s3) REC(A7, A6, A5) M8(A7, bfA)
    REC(A8, A7, A6) M8(A8, bfB)
  }
#undef REC
#undef LB
#undef M8
#undef ADOPT
#undef VMB

  // epilogue: C/D map col=lane&31, row=(j&3)+8*(j>>2)+4*(lane>>5); add bias
  float bno[2];
  bno[0] = bias[n0 + lr];
  bno[1] = bias[n0 + 32 + lr];
#pragma unroll
  for (int mb = 0; mb < 2; ++mb)
#pragma unroll
    for (int nb = 0; nb < 2; ++nb)
#pragma unroll
      for (int j = 0; j < 16; ++j) {
        int row = m0 + mb * 32 + 4 * lh + (j & 3) + 8 * (j >> 2);
        int col = n0 + nb * 32 + lr;
        out[(size_t)row * 1024 + col] = acc[mb][nb][j] * INV_WSCALE + bno[nb];
      }
}

// ---- fallback (ws too small): in-GEMM tanh, full 9 degrees, chunk-level sync
__global__ __launch_bounds__(512, 2) void cheby_gemm_fb(const float* __restrict__ x,
                                                        const f16* __restrict__ wt,
                                                        float* __restrict__ out) {
  __shared__ f16 bbuf[18][4096];
  const int tid  = threadIdx.x;
  const int wid  = tid >> 6;
  const int lane = tid & 63;
  const int lr   = lane & 31;
  const int lh   = lane >> 5;
  const int wm   = wid >> 1;
  const int wn   = wid & 1;
  const int mrow = blockIdx.x >> 3;
  const int ncol = blockIdx.x & 7;
  const int m0   = mrow * 256 + wm * 64;
  const int n0   = ncol * 128 + wn * 64;
  const int rbase = wn * 2048 + ((lane & 15) * 4 + ((lane >> 4) ^ ((lane >> 1) & 3))) * 8;

  auto stage = [&](int cn, int dn, int buf) {
    const f16* src = wt + (size_t)(dn * 32 + cn) * 32768 + (size_t)ncol * 4096;
    __builtin_amdgcn_global_load_lds(
        (const __attribute__((address_space(1))) unsigned*)(src + tid * 8),
        (__attribute__((address_space(3))) unsigned*)(&bbuf[buf][wid * 512]),
        16, 0, 0);
  };
  auto stage9 = [&](int cn, int b0) {
#pragma unroll
    for (int d = 0; d < 9; ++d) stage(cn, d, b0 + d);
  };

  f32x16 acc[2][2];
#pragma unroll
  for (int a = 0; a < 2; ++a)
#pragma unroll
    for (int b = 0; b < 2; ++b)
#pragma unroll
      for (int j = 0; j < 16; ++j) acc[a][b][j] = 0.f;

  const f16x8 ones  = {(f16)1,(f16)1,(f16)1,(f16)1,(f16)1,(f16)1,(f16)1,(f16)1};
  const f16x8 half8 = {(f16)0.5f,(f16)0.5f,(f16)0.5f,(f16)0.5f,
                       (f16)0.5f,(f16)0.5f,(f16)0.5f,(f16)0.5f};
  f16x8 t2v[2][2], t2n[2][2];
  f32x4 xf[2][2][2];

  auto loadx = [&](int cn) {
#pragma unroll
    for (int mb = 0; mb < 2; ++mb)
#pragma unroll
      for (int h = 0; h < 2; ++h) {
        const float* p = x + (size_t)(m0 + mb * 32 + lr) * 1024 + cn * 32 + h * 16 + lh * 8;
        xf[mb][h][0] = *(const f32x4*)p;
        xf[mb][h][1] = *(const f32x4*)(p + 4);
      }
  };
  auto dotanh = [&]() {
#pragma unroll
    for (int mb = 0; mb < 2; ++mb)
#pragma unroll
      for (int h = 0; h < 2; ++h) {
        float tf[8];
#pragma unroll
        for (int e = 0; e < 8; ++e) {
          float xx = (e < 4) ? xf[mb][h][0][e] : xf[mb][h][1][e - 4];
          tf[e] = 1.f - 2.f * __builtin_amdgcn_rcpf(__expf(2.f * xx) + 1.f);
        }
        F16x8u u;
#pragma unroll
        for (int q = 0; q < 4; ++q)
          u.h2[q] = __builtin_amdgcn_cvt_pkrtz(tf[2 * q], tf[2 * q + 1]);
        t2n[mb][h] = u.v8 + u.v8;
      }
  };

#define REC(NEW, S1, S2)                                                       \
  _Pragma("unroll") for (int mb = 0; mb < 2; ++mb)                             \
    _Pragma("unroll") for (int h = 0; h < 2; ++h)                              \
      NEW[mb][h] = __builtin_elementwise_fma(t2v[mb][h], S1[mb][h], -S2[mb][h]);
#define CLUSTER(AF, DIDX)                                                      \
  {                                                                            \
    const f16* bb = &bbuf[0][0] + sbase + (DIDX) * 4096 + rbase;               \
    f16x8 bf[2][2];                                                            \
    _Pragma("unroll") for (int nb = 0; nb < 2; ++nb)                           \
      _Pragma("unroll") for (int h = 0; h < 2; ++h)                            \
        bf[nb][h] = *(const f16x8*)&bb[nb * 1024 + h * 512];                   \
    _Pragma("unroll") for (int nb = 0; nb < 2; ++nb)                           \
      _Pragma("unroll") for (int mb = 0; mb < 2; ++mb) {                       \
        acc[mb][nb] = __builtin_amdgcn_mfma_f32_32x32x16_f16(AF[mb][0], bf[nb][0], \
                                                             acc[mb][nb], 0, 0, 0); \
        acc[mb][nb] = __builtin_amdgcn_mfma_f32_32x32x16_f16(AF[mb][1], bf[nb][1], \
                                                             acc[mb][nb], 0, 0, 0); \
      }                                                                        \
  }

  stage9(0, 0);
  loadx(0);
  dotanh();

  f16x8 onesA[2][2];
#pragma unroll
  for (int mb = 0; mb < 2; ++mb)
#pragma unroll
    for (int h = 0; h < 2; ++h) onesA[mb][h] = ones;

  for (int c = 0; c < 32; ++c) {
    const bool lastc = (c == 31);
    const int  sbase = (c & 1) * 36864;
    const int  nbase = (1 - (c & 1)) * 9;

    asm volatile("s_waitcnt vmcnt(8)" ::: "memory");
    __builtin_amdgcn_s_barrier();

    f16x8 A1[2][2], A2[2][2], A3[2][2], A4[2][2], A5[2][2], A6[2][2], A7[2][2], A8[2][2];
#pragma unroll
    for (int mb = 0; mb < 2; ++mb)
#pragma unroll
      for (int h = 0; h < 2; ++h) {
        t2v[mb][h] = t2n[mb][h];
        A1[mb][h]  = t2v[mb][h] * half8;
      }
    if (!lastc) { stage9(c + 1, nbase); loadx(c + 1); }

    CLUSTER(onesA, 0)
    CLUSTER(A1, 1)
    REC(A2, A1, onesA)  CLUSTER(A2, 2)
    REC(A3, A2, A1)     CLUSTER(A3, 3)
    REC(A4, A3, A2)     CLUSTER(A4, 4)
    REC(A5, A4, A3)     CLUSTER(A5, 5)
    REC(A6, A5, A4)     CLUSTER(A6, 6)
    REC(A7, A6, A5)     CLUSTER(A7, 7)
    REC(A8, A7, A6)     CLUSTER(A8, 8)
    if (!lastc) dotanh();
  }
#undef REC
#undef CLUSTER

#pragma unroll
  for (int mb = 0; mb < 2; ++mb)
#pragma unroll
    for (int nb = 0; nb < 2; ++nb)
#pragma unroll
      for (int j = 0; j < 16; ++j) {
        int row = m0 + mb * 32 + 4 * lh + (j & 3) + 8 * (j >> 2);
        int col = n0 + nb * 32 + lr;
        out[(size_t)row * 1024 + col] = acc[mb][nb][j] * INV_WSCALE;
      }
}

extern "C" void kernel_launch(void* const* d_in, const int* in_sizes, int n_in,
                              void* d_out, int out_size, void* d_ws, size_t ws_size,
                              hipStream_t stream) {
  const float* x  = (const float*)d_in[0];
  const float* cc = (const float*)d_in[1];
  f16*   wt   = (f16*)d_ws;                          // 18,874,368 B
  f16*   t2   = (f16*)((char*)d_ws + 18874368);      // 33,554,432 B
  float* bias = (float*)((char*)d_ws + 52428800);    // 4,096 B
  float* out  = (float*)d_out;

  if (ws_size >= 52432896) {
    hipLaunchKernelGGL(prep_kernel, dim3(9280), dim3(256), 0, stream, x, cc, t2, wt, bias);
    hipLaunchKernelGGL(cheby_gemm, dim3(1024), dim3(256), 0, stream, t2, wt, bias, out);
  } else {
    hipLaunchKernelGGL(prep_kernel, dim3(1024), dim3(256), 0, stream, x, cc, t2, wt, bias);
    hipLaunchKernelGGL(cheby_gemm_fb, dim3(512), dim3(512), 0, stream, x, wt, out);
  }
}